// Round 1
// baseline (151.652 us; speedup 1.0000x reference)
//
#include <hip/hip_runtime.h>
#include <hip/hip_bf16.h>

#define B_   16384
#define F_   26
#define N_   100000
#define M_   16
#define NUM_ 13
#define D_   429
#define DP_  448     // padded K for GEMM1 (multiple of 64)
#define L_   6
#define H_   1024

typedef unsigned short u16;
typedef __bf16 bf16x8 __attribute__((ext_vector_type(8)));
typedef float  f32x4  __attribute__((ext_vector_type(4)));

__device__ __forceinline__ u16 f2bf_bits(float f) {
  union { float f; unsigned u; } x; x.f = f;
  unsigned r = x.u + 0x7FFFu + ((x.u >> 16) & 1u);   // RNE
  return (u16)(r >> 16);
}
__device__ __forceinline__ float bfbits2f(u16 b) {
  union { unsigned u; float f; } x; x.u = ((unsigned)b) << 16;
  return x.f;
}

// Build x0 in permuted padded layout: [ g(0..415) | Xv(416..428) | zeros(429..447) ]
// orig index d -> padded e:  d<13 -> 416+d ; d>=13 -> d-13
__global__ void build_x0(const int* __restrict__ Xi, const float* __restrict__ Xv,
                         const float* __restrict__ emb,
                         float* __restrict__ x0f, u16* __restrict__ x0b) {
  int t = blockIdx.x * blockDim.x + threadIdx.x;
  int b = t / (F_ + 1);
  int f = t % (F_ + 1);
  if (b >= B_) return;
  if (f < F_) {
    int idx = Xi[b * F_ + f];
    const float4* src = (const float4*)(emb + ((size_t)f * N_ + idx) * M_);
    float4 v[4];
    v[0] = src[0]; v[1] = src[1]; v[2] = src[2]; v[3] = src[3];
    float* df = x0f + (size_t)b * DP_ + f * 16;
    ((float4*)df)[0] = v[0]; ((float4*)df)[1] = v[1];
    ((float4*)df)[2] = v[2]; ((float4*)df)[3] = v[3];
    u16 u[16];
    #pragma unroll
    for (int i = 0; i < 16; ++i) u[i] = f2bf_bits(((const float*)v)[i]);
    uint4* db = (uint4*)(x0b + (size_t)b * DP_ + f * 16);
    db[0] = *(const uint4*)&u[0];
    db[1] = *(const uint4*)&u[8];
  } else {
    float* df = x0f + (size_t)b * DP_ + 416;
    u16*   db = x0b + (size_t)b * DP_ + 416;
    #pragma unroll
    for (int i = 0; i < NUM_; ++i) {
      float v = Xv[b * NUM_ + i];
      df[i] = v; db[i] = f2bf_bits(v);
    }
    #pragma unroll
    for (int i = NUM_; i < 32; ++i) { df[i] = 0.f; db[i] = 0; }
  }
}

// W1 [429,1024] fp32 -> W1bt [1024,448] bf16, K-major, permuted+padded rows
__global__ void prep_w1(const float* __restrict__ W1, u16* __restrict__ W1bt) {
  int t = blockIdx.x * blockDim.x + threadIdx.x;
  if (t >= H_ * DP_) return;
  int n = t / DP_, e = t % DP_;
  float v = 0.f;
  if (e < D_) {
    int d = (e < 416) ? (13 + e) : (e - 416);
    v = W1[(size_t)d * H_ + n];
  }
  W1bt[t] = f2bf_bits(v);
}

// W2 [1024,1024] fp32 -> W2bt [1024,1024] bf16 transposed
__global__ void prep_w2(const float* __restrict__ W2, u16* __restrict__ W2bt) {
  int t = blockIdx.x * blockDim.x + threadIdx.x;
  if (t >= H_ * H_) return;
  int n = t / H_, k = t % H_;
  W2bt[t] = f2bf_bits(W2[(size_t)k * H_ + n]);
}

// CrossNet, fp32, one wave per row, x held in registers (7 elems/lane over 448)
__global__ __launch_bounds__(256) void crossnet(const float* __restrict__ x0f,
                                                const float* __restrict__ cw,
                                                const float* __restrict__ cb,
                                                float* __restrict__ xout) {
  int w = threadIdx.x >> 6, lane = threadIdx.x & 63;
  int b = blockIdx.x * 4 + w;
  const float* row = x0f + (size_t)b * DP_;
  float x0r[7], xr[7];
  #pragma unroll
  for (int i = 0; i < 7; ++i) { x0r[i] = row[i * 64 + lane]; xr[i] = x0r[i]; }
  for (int l = 0; l < L_; ++l) {
    float wl[7], bl[7];
    #pragma unroll
    for (int i = 0; i < 7; ++i) {
      int e = i * 64 + lane;
      if (e < D_) {
        int d = (e < 416) ? (13 + e) : (e - 416);
        wl[i] = cw[l * D_ + d]; bl[i] = cb[l * D_ + d];
      } else { wl[i] = 0.f; bl[i] = 0.f; }
    }
    float s = 0.f;
    #pragma unroll
    for (int i = 0; i < 7; ++i) s += xr[i] * wl[i];
    #pragma unroll
    for (int off = 32; off; off >>= 1) s += __shfl_xor(s, off);
    #pragma unroll
    for (int i = 0; i < 7; ++i) xr[i] = x0r[i] * s + bl[i] + xr[i];
  }
  float* orow = xout + (size_t)b * DP_;
  #pragma unroll
  for (int i = 0; i < 7; ++i) orow[i * 64 + lane] = xr[i];
}

// C[M,N] = relu(A[M,Kp] @ BT[N,Kp]^T + bias), bf16 in, bf16 out, fp32 accum.
// m97 structure: 128x128 tile, BK=64, 4 waves (2x2), global_load_lds width 16.
__global__ __launch_bounds__(256) void gemm_bt(const u16* __restrict__ A,
                                               const u16* __restrict__ BT,
                                               const float* __restrict__ bias,
                                               u16* __restrict__ C,
                                               int M, int N, int Kp) {
  __shared__ __align__(16) u16 As[128 * 64];
  __shared__ __align__(16) u16 Bs[128 * 64];
  int nbx = N >> 7;
  int bx = blockIdx.x % nbx;
  int by = blockIdx.x / nbx;
  int tid = threadIdx.x;
  int w = tid >> 6, lane = tid & 63;
  int wr = w >> 1, wc = w & 1;

  f32x4 acc[4][4] = {};

  const u16* ga0 = A  + (size_t)(by * 128 + w * 8 + (lane >> 3)) * Kp + (lane & 7) * 8;
  const u16* gb0 = BT + (size_t)(bx * 128 + w * 8 + (lane >> 3)) * Kp + (lane & 7) * 8;
  int nkt = Kp >> 6;
  for (int kt = 0; kt < nkt; ++kt) {
    const u16* ga = ga0 + kt * 64;
    const u16* gb = gb0 + kt * 64;
    #pragma unroll
    for (int i = 0; i < 4; ++i) {
      __builtin_amdgcn_global_load_lds(
          (const __attribute__((address_space(1))) void*)(ga + (size_t)i * 32 * Kp),
          (__attribute__((address_space(3))) void*)&As[(w * 8 + i * 32) * 64], 16, 0, 0);
    }
    #pragma unroll
    for (int i = 0; i < 4; ++i) {
      __builtin_amdgcn_global_load_lds(
          (const __attribute__((address_space(1))) void*)(gb + (size_t)i * 32 * Kp),
          (__attribute__((address_space(3))) void*)&Bs[(w * 8 + i * 32) * 64], 16, 0, 0);
    }
    __syncthreads();
    #pragma unroll
    for (int kk = 0; kk < 2; ++kk) {
      bf16x8 af[4], bf[4];
      #pragma unroll
      for (int m = 0; m < 4; ++m)
        af[m] = *(const bf16x8*)&As[(wr * 64 + m * 16 + (lane & 15)) * 64 + kk * 32 + (lane >> 4) * 8];
      #pragma unroll
      for (int n = 0; n < 4; ++n)
        bf[n] = *(const bf16x8*)&Bs[(wc * 64 + n * 16 + (lane & 15)) * 64 + kk * 32 + (lane >> 4) * 8];
      #pragma unroll
      for (int m = 0; m < 4; ++m)
        #pragma unroll
        for (int n = 0; n < 4; ++n)
          acc[m][n] = __builtin_amdgcn_mfma_f32_16x16x32_bf16(af[m], bf[n], acc[m][n], 0, 0, 0);
    }
    __syncthreads();
  }
  int crow0 = by * 128 + wr * 64;
  int ccol0 = bx * 128 + wc * 64;
  #pragma unroll
  for (int n = 0; n < 4; ++n) {
    int col = ccol0 + n * 16 + (lane & 15);
    float bv = bias[col];
    #pragma unroll
    for (int m = 0; m < 4; ++m) {
      #pragma unroll
      for (int r = 0; r < 4; ++r) {
        int row = crow0 + m * 16 + (lane >> 4) * 4 + r;
        float v = acc[m][n][r] + bv;
        v = fmaxf(v, 0.f);
        C[(size_t)row * N + col] = f2bf_bits(v);
      }
    }
  }
}

// out[b] = h2[b,:]·Wout[0:1024] + x[b,perm]·Wout[1024+d] + bout
__global__ __launch_bounds__(256) void final_dot(const u16* __restrict__ h2,
                                                 const float* __restrict__ xf,
                                                 const float* __restrict__ Wout,
                                                 const float* __restrict__ bout,
                                                 float* __restrict__ out) {
  int w = threadIdx.x >> 6, lane = threadIdx.x & 63;
  int b = blockIdx.x * 4 + w;
  const u16* hrow = h2 + (size_t)b * H_;
  float s = 0.f;
  #pragma unroll
  for (int i = 0; i < 16; ++i) {
    int e = i * 64 + lane;
    s += bfbits2f(hrow[e]) * Wout[e];
  }
  const float* xrow = xf + (size_t)b * DP_;
  #pragma unroll
  for (int i = 0; i < 7; ++i) {
    int e = i * 64 + lane;
    if (e < D_) {
      int d = (e < 416) ? (13 + e) : (e - 416);
      s += xrow[e] * Wout[H_ + d];
    }
  }
  #pragma unroll
  for (int off = 32; off; off >>= 1) s += __shfl_xor(s, off);
  if (lane == 0) out[b] = s + bout[0];
}

extern "C" void kernel_launch(void* const* d_in, const int* in_sizes, int n_in,
                              void* d_out, int out_size, void* d_ws, size_t ws_size,
                              hipStream_t stream) {
  const int*   Xi   = (const int*)d_in[0];
  const float* Xv   = (const float*)d_in[1];
  const float* emb  = (const float*)d_in[2];
  const float* cw   = (const float*)d_in[3];
  const float* cb   = (const float*)d_in[4];
  const float* W1   = (const float*)d_in[5];
  const float* b1   = (const float*)d_in[6];
  const float* W2   = (const float*)d_in[7];
  const float* b2   = (const float*)d_in[8];
  const float* Wout = (const float*)d_in[9];
  const float* bout = (const float*)d_in[10];
  float* out = (float*)d_out;

  char* ws = (char*)d_ws;
  size_t off = 0;
  auto alloc = [&](size_t bytes) {
    void* p = ws + off; off += (bytes + 255) & ~(size_t)255; return p;
  };
  float* x0f  = (float*)alloc((size_t)B_ * DP_ * 4);
  u16*   x0b  = (u16*)  alloc((size_t)B_ * DP_ * 2);
  float* xf   = (float*)alloc((size_t)B_ * DP_ * 4);
  u16*   w1bt = (u16*)  alloc((size_t)H_ * DP_ * 2);
  u16*   w2bt = (u16*)  alloc((size_t)H_ * H_ * 2);
  u16*   h1   = (u16*)  alloc((size_t)B_ * H_ * 2);
  u16*   h2   = (u16*)  alloc((size_t)B_ * H_ * 2);

  hipLaunchKernelGGL(build_x0, dim3((B_ * (F_ + 1) + 255) / 256), dim3(256), 0, stream,
                     Xi, Xv, emb, x0f, x0b);
  hipLaunchKernelGGL(prep_w1, dim3((H_ * DP_ + 255) / 256), dim3(256), 0, stream, W1, w1bt);
  hipLaunchKernelGGL(prep_w2, dim3((H_ * H_ + 255) / 256), dim3(256), 0, stream, W2, w2bt);
  hipLaunchKernelGGL(crossnet, dim3(B_ / 4), dim3(256), 0, stream, x0f, cw, cb, xf);
  hipLaunchKernelGGL(gemm_bt, dim3((B_ / 128) * (H_ / 128)), dim3(256), 0, stream,
                     x0b, w1bt, b1, h1, B_, H_, DP_);
  hipLaunchKernelGGL(gemm_bt, dim3((B_ / 128) * (H_ / 128)), dim3(256), 0, stream,
                     h1, w2bt, b2, h2, B_, H_, H_);
  hipLaunchKernelGGL(final_dot, dim3(B_ / 4), dim3(256), 0, stream, h2, xf, Wout, bout, out);
}

// Round 2
// 132.166 us; speedup vs baseline: 1.1474x; 1.1474x over previous
//
#include <hip/hip_runtime.h>
#include <hip/hip_bf16.h>

#define B_   16384
#define F_   26
#define N_   100000
#define M_   16
#define NUM_ 13
#define D_   429
#define DP_  448     // x0f (fp32) row stride
#define KP1_ 512     // padded K for GEMM1 (bf16 operand)
#define L_   6
#define H_   1024

typedef unsigned short u16;
typedef __bf16 bf16x8 __attribute__((ext_vector_type(8)));
typedef float  f32x4  __attribute__((ext_vector_type(4)));

__device__ __forceinline__ u16 f2bf_bits(float f) {
  union { float f; unsigned u; } x; x.f = f;
  unsigned r = x.u + 0x7FFFu + ((x.u >> 16) & 1u);   // RNE
  return (u16)(r >> 16);
}

// x0 permuted layout: [ g(0..415) | Xv(416..428) | zeros ]  (orig d<13 -> 416+d ; d>=13 -> d-13)
__global__ void build_x0(const int* __restrict__ Xi, const float* __restrict__ Xv,
                         const float* __restrict__ emb,
                         float* __restrict__ x0f, u16* __restrict__ x0b) {
  int t = blockIdx.x * blockDim.x + threadIdx.x;
  int b = t / (F_ + 1);
  int f = t % (F_ + 1);
  if (b >= B_) return;
  if (f < F_) {
    int idx = Xi[b * F_ + f];
    const float4* src = (const float4*)(emb + ((size_t)f * N_ + idx) * M_);
    float4 v[4];
    v[0] = src[0]; v[1] = src[1]; v[2] = src[2]; v[3] = src[3];
    float* df = x0f + (size_t)b * DP_ + f * 16;
    ((float4*)df)[0] = v[0]; ((float4*)df)[1] = v[1];
    ((float4*)df)[2] = v[2]; ((float4*)df)[3] = v[3];
    u16 u[16];
    #pragma unroll
    for (int i = 0; i < 16; ++i) u[i] = f2bf_bits(((const float*)v)[i]);
    uint4* db = (uint4*)(x0b + (size_t)b * KP1_ + f * 16);
    db[0] = *(const uint4*)&u[0];
    db[1] = *(const uint4*)&u[8];
  } else {
    float* df = x0f + (size_t)b * DP_ + 416;
    u16*   db = x0b + (size_t)b * KP1_ + 416;
    #pragma unroll
    for (int i = 0; i < NUM_; ++i) {
      float v = Xv[b * NUM_ + i];
      df[i] = v; db[i] = f2bf_bits(v);
    }
    #pragma unroll
    for (int i = NUM_; i < 32; ++i) df[i] = 0.f;
    for (int i = NUM_; i < KP1_ - 416; ++i) db[i] = 0;
  }
}

// W1 [429,1024] fp32 -> W1bt [1024,512] bf16, K-major, permuted+padded
__global__ void prep_w1(const float* __restrict__ W1, u16* __restrict__ W1bt) {
  int t = blockIdx.x * blockDim.x + threadIdx.x;
  if (t >= H_ * KP1_) return;
  int n = t / KP1_, e = t % KP1_;
  float v = 0.f;
  if (e < D_) {
    int d = (e < 416) ? (13 + e) : (e - 416);
    v = W1[(size_t)d * H_ + n];
  }
  W1bt[t] = f2bf_bits(v);
}

// W2 [1024,1024] fp32 -> W2bt bf16 transposed
__global__ void prep_w2(const float* __restrict__ W2, u16* __restrict__ W2bt) {
  int t = blockIdx.x * blockDim.x + threadIdx.x;
  if (t >= H_ * H_) return;
  int n = t / H_, k = t % H_;
  W2bt[t] = f2bf_bits(W2[(size_t)k * H_ + n]);
}

// CrossNet fp32 (1 wave/row) + initializes out[b] with the x-tail of the final dot.
__global__ __launch_bounds__(256) void crossnet(const float* __restrict__ x0f,
                                                const float* __restrict__ cw,
                                                const float* __restrict__ cb,
                                                const float* __restrict__ Wout,
                                                const float* __restrict__ bout,
                                                float* __restrict__ out) {
  int w = threadIdx.x >> 6, lane = threadIdx.x & 63;
  int b = blockIdx.x * 4 + w;
  const float* row = x0f + (size_t)b * DP_;
  float x0r[7], xr[7];
  #pragma unroll
  for (int i = 0; i < 7; ++i) { x0r[i] = row[i * 64 + lane]; xr[i] = x0r[i]; }
  for (int l = 0; l < L_; ++l) {
    float wl[7], bl[7];
    #pragma unroll
    for (int i = 0; i < 7; ++i) {
      int e = i * 64 + lane;
      if (e < D_) {
        int d = (e < 416) ? (13 + e) : (e - 416);
        wl[i] = cw[l * D_ + d]; bl[i] = cb[l * D_ + d];
      } else { wl[i] = 0.f; bl[i] = 0.f; }
    }
    float s = 0.f;
    #pragma unroll
    for (int i = 0; i < 7; ++i) s += xr[i] * wl[i];
    #pragma unroll
    for (int off = 32; off; off >>= 1) s += __shfl_xor(s, off);
    #pragma unroll
    for (int i = 0; i < 7; ++i) xr[i] = x0r[i] * s + bl[i] + xr[i];
  }
  // tail of final dot: x . Wout[H_ + d]  + bout
  float s = 0.f;
  #pragma unroll
  for (int i = 0; i < 7; ++i) {
    int e = i * 64 + lane;
    if (e < D_) {
      int d = (e < 416) ? (13 + e) : (e - 416);
      s += xr[i] * Wout[H_ + d];
    }
  }
  #pragma unroll
  for (int off = 32; off; off >>= 1) s += __shfl_xor(s, off);
  if (lane == 0) out[b] = s + bout[0];
}

// 256x256 tile, BK=32, 8 waves (2x4), 4-buffer LDS ring, counted vmcnt, T2 swizzle.
// MODE 0: C = bf16(relu(A@BT^T + bias)).  MODE 1: out[row] += sum_col relu(.)*Wout[col].
template<int MODE>
__global__ __launch_bounds__(512, 2) void gemm256(
    const u16* __restrict__ A, const u16* __restrict__ BT,
    const float* __restrict__ bias, u16* __restrict__ C,
    const float* __restrict__ Wout, float* __restrict__ out,
    int N, int K) {
  __shared__ __align__(16) u16 As[4][256 * 32];
  __shared__ __align__(16) u16 Bs[4][256 * 32];
  const int nbx = N >> 8;
  const int bx = blockIdx.x % nbx;
  const int by = blockIdx.x / nbx;
  const int tid = threadIdx.x;
  const int w = tid >> 6, l = tid & 63;
  const int wr = w >> 2, wc = w & 3;
  const int nkt = K >> 5;

  // staging: lane l covers (row = w*16 + l>>2, chunk = l&3); source chunk pre-swizzled
  const int srow = l >> 2;
  const int schunk = (l & 3) ^ ((l >> 3) & 3);
  const u16* gA = A  + (size_t)(by * 256 + w * 16 + srow) * K + schunk * 8;
  const u16* gB = BT + (size_t)(bx * 256 + w * 16 + srow) * K + schunk * 8;
  const int ldsoff = w * 16 * 32;   // u16 units

  auto stage = [&](int t) {
    const int buf = t & 3;
    const u16* a = gA + t * 32;
    const u16* b = gB + t * 32;
    #pragma unroll
    for (int i = 0; i < 2; ++i)
      __builtin_amdgcn_global_load_lds(
          (const __attribute__((address_space(1))) void*)(a + (size_t)i * 128 * K),
          (__attribute__((address_space(3))) void*)&As[buf][ldsoff + i * 128 * 32], 16, 0, 0);
    #pragma unroll
    for (int i = 0; i < 2; ++i)
      __builtin_amdgcn_global_load_lds(
          (const __attribute__((address_space(1))) void*)(b + (size_t)i * 128 * K),
          (__attribute__((address_space(3))) void*)&Bs[buf][ldsoff + i * 128 * 32], 16, 0, 0);
  };

  stage(0); stage(1); stage(2);

  // fragment read offsets (bytes), swizzle: phys = lin ^ (((row>>1)&3)<<4)
  const int fr = l & 15;
  const int fs = ((l >> 4) ^ ((fr >> 1) & 3)) << 4;
  const int aoff = (wr * 128 + fr) * 64 + fs;
  const int boff = (wc * 64 + fr) * 64 + fs;

  f32x4 acc[8][4] = {};

  asm volatile("s_waitcnt vmcnt(8)" ::: "memory");
  __builtin_amdgcn_s_barrier();

  for (int t = 0; t < nkt; ++t) {
    if (t + 3 < nkt) stage(t + 3);
    const char* Ab = (const char*)&As[t & 3][0];
    const char* Bb = (const char*)&Bs[t & 3][0];
    bf16x8 af[8], bf[4];
    #pragma unroll
    for (int m = 0; m < 8; ++m) af[m] = *(const bf16x8*)(Ab + aoff + m * 1024);
    #pragma unroll
    for (int n = 0; n < 4; ++n) bf[n] = *(const bf16x8*)(Bb + boff + n * 1024);
    __builtin_amdgcn_s_setprio(1);
    #pragma unroll
    for (int m = 0; m < 8; ++m)
      #pragma unroll
      for (int n = 0; n < 4; ++n)
        acc[m][n] = __builtin_amdgcn_mfma_f32_16x16x32_bf16(af[m], bf[n], acc[m][n], 0, 0, 0);
    __builtin_amdgcn_s_setprio(0);
    if (t + 3 < nkt)      asm volatile("s_waitcnt vmcnt(8)" ::: "memory");
    else if (t + 2 < nkt) asm volatile("s_waitcnt vmcnt(4)" ::: "memory");
    else if (t + 1 < nkt) asm volatile("s_waitcnt vmcnt(0)" ::: "memory");
    if (t + 1 < nkt) __builtin_amdgcn_s_barrier();
  }

  const int g4 = l >> 4;
  const int ccol0 = bx * 256 + wc * 64;
  const int row0 = by * 256 + wr * 128 + g4 * 4;
  if (MODE == 0) {
    #pragma unroll
    for (int n = 0; n < 4; ++n) {
      int col = ccol0 + n * 16 + fr;
      float bv = bias[col];
      #pragma unroll
      for (int m = 0; m < 8; ++m)
        #pragma unroll
        for (int r = 0; r < 4; ++r) {
          float v = fmaxf(acc[m][n][r] + bv, 0.f);
          C[(size_t)(row0 + m * 16 + r) * N + col] = f2bf_bits(v);
        }
    }
  } else {
    float bv[4], wv[4];
    #pragma unroll
    for (int n = 0; n < 4; ++n) {
      int col = ccol0 + n * 16 + fr;
      bv[n] = bias[col]; wv[n] = Wout[col];
    }
    #pragma unroll
    for (int m = 0; m < 8; ++m)
      #pragma unroll
      for (int r = 0; r < 4; ++r) {
        float s = 0.f;
        #pragma unroll
        for (int n = 0; n < 4; ++n) {
          float v = fmaxf(acc[m][n][r] + bv[n], 0.f);
          s = fmaf(v, wv[n], s);
        }
        s += __shfl_xor(s, 1); s += __shfl_xor(s, 2);
        s += __shfl_xor(s, 4); s += __shfl_xor(s, 8);
        if (fr == 0) atomicAdd(out + row0 + m * 16 + r, s);
      }
  }
}

extern "C" void kernel_launch(void* const* d_in, const int* in_sizes, int n_in,
                              void* d_out, int out_size, void* d_ws, size_t ws_size,
                              hipStream_t stream) {
  const int*   Xi   = (const int*)d_in[0];
  const float* Xv   = (const float*)d_in[1];
  const float* emb  = (const float*)d_in[2];
  const float* cw   = (const float*)d_in[3];
  const float* cb   = (const float*)d_in[4];
  const float* W1   = (const float*)d_in[5];
  const float* b1   = (const float*)d_in[6];
  const float* W2   = (const float*)d_in[7];
  const float* b2   = (const float*)d_in[8];
  const float* Wout = (const float*)d_in[9];
  const float* bout = (const float*)d_in[10];
  float* out = (float*)d_out;

  char* ws = (char*)d_ws;
  size_t off = 0;
  auto alloc = [&](size_t bytes) {
    void* p = ws + off; off += (bytes + 255) & ~(size_t)255; return p;
  };
  float* x0f  = (float*)alloc((size_t)B_ * DP_ * 4);
  u16*   x0b  = (u16*)  alloc((size_t)B_ * KP1_ * 2);
  u16*   w1bt = (u16*)  alloc((size_t)H_ * KP1_ * 2);
  u16*   w2bt = (u16*)  alloc((size_t)H_ * H_ * 2);
  u16*   h1   = (u16*)  alloc((size_t)B_ * H_ * 2);

  hipLaunchKernelGGL(build_x0, dim3((B_ * (F_ + 1) + 255) / 256), dim3(256), 0, stream,
                     Xi, Xv, emb, x0f, x0b);
  hipLaunchKernelGGL(prep_w1, dim3((H_ * KP1_ + 255) / 256), dim3(256), 0, stream, W1, w1bt);
  hipLaunchKernelGGL(prep_w2, dim3((H_ * H_ + 255) / 256), dim3(256), 0, stream, W2, w2bt);
  hipLaunchKernelGGL(crossnet, dim3(B_ / 4), dim3(256), 0, stream,
                     x0f, cw, cb, Wout, bout, out);
  hipLaunchKernelGGL((gemm256<0>), dim3((B_ / 256) * (H_ / 256)), dim3(512), 0, stream,
                     x0b, w1bt, b1, h1, nullptr, nullptr, H_, KP1_);
  hipLaunchKernelGGL((gemm256<1>), dim3((B_ / 256) * (H_ / 256)), dim3(512), 0, stream,
                     h1, w2bt, b2, nullptr, Wout, out, H_, H_);
}

// Round 3
// 114.130 us; speedup vs baseline: 1.3288x; 1.1580x over previous
//
#include <hip/hip_runtime.h>
#include <hip/hip_bf16.h>

#define B_   16384
#define F_   26
#define N_   100000
#define M_   16
#define NUM_ 13
#define D_   429
#define KP1_ 448     // padded K for GEMM1 (bf16 operand), multiple of 32
#define L_   6
#define H_   1024

typedef unsigned short u16;
typedef __bf16 bf16x8 __attribute__((ext_vector_type(8)));
typedef float  f32x4  __attribute__((ext_vector_type(4)));

__device__ __forceinline__ u16 f2bf_bits(float f) {
  union { float f; unsigned u; } x; x.f = f;
  unsigned r = x.u + 0x7FFFu + ((x.u >> 16) & 1u);   // RNE
  return (u16)(r >> 16);
}

// Fused: embedding gather -> x0 (registers) -> bf16 x0 row (for GEMM1)
//        -> CrossNet (fp32, in-register) -> out[b] = x . Wout[1024+d] + bout
// x0 permuted layout: [ g(0..415) | Xv(416..428) | zeros(429..447) ]
//   orig d<13 -> 416+d ; d>=13 -> d-13
__global__ __launch_bounds__(256) void build_cross(
    const int* __restrict__ Xi, const float* __restrict__ Xv,
    const float* __restrict__ emb,
    const float* __restrict__ cw, const float* __restrict__ cb,
    const float* __restrict__ Wout, const float* __restrict__ bout,
    u16* __restrict__ x0b, float* __restrict__ out) {
  __shared__ u16 sbuf[4][KP1_];
  const int w = threadIdx.x >> 6, lane = threadIdx.x & 63;
  const int b = blockIdx.x * 4 + w;
  const int* xi = Xi + b * F_;

  float x0r[7];
  #pragma unroll
  for (int i = 0; i < 7; ++i) {
    int e = i * 64 + lane;
    float v = 0.f;
    if (e < 416) {
      int f = e >> 4;
      int idx = xi[f];
      v = emb[((size_t)f * N_ + idx) * M_ + (e & 15)];
    } else if (e < D_) {
      v = Xv[b * NUM_ + (e - 416)];
    }
    x0r[i] = v;
    sbuf[w][e] = f2bf_bits(v);
  }

  float xr[7];
  #pragma unroll
  for (int i = 0; i < 7; ++i) xr[i] = x0r[i];
  for (int l = 0; l < L_; ++l) {
    float wl[7], bl[7];
    #pragma unroll
    for (int i = 0; i < 7; ++i) {
      int e = i * 64 + lane;
      if (e < D_) {
        int d = (e < 416) ? (13 + e) : (e - 416);
        wl[i] = cw[l * D_ + d]; bl[i] = cb[l * D_ + d];
      } else { wl[i] = 0.f; bl[i] = 0.f; }
    }
    float s = 0.f;
    #pragma unroll
    for (int i = 0; i < 7; ++i) s += xr[i] * wl[i];
    #pragma unroll
    for (int off = 32; off; off >>= 1) s += __shfl_xor(s, off);
    #pragma unroll
    for (int i = 0; i < 7; ++i) xr[i] = x0r[i] * s + bl[i] + xr[i];
  }

  __syncthreads();
  // vectorized bf16 row store: 448 u16 = 56 uint4
  if (lane < 56)
    ((uint4*)(x0b + (size_t)b * KP1_))[lane] = ((const uint4*)sbuf[w])[lane];

  // tail of final dot: x . Wout[H_ + d] + bout
  float s = 0.f;
  #pragma unroll
  for (int i = 0; i < 7; ++i) {
    int e = i * 64 + lane;
    if (e < D_) {
      int d = (e < 416) ? (13 + e) : (e - 416);
      s += xr[i] * Wout[H_ + d];
    }
  }
  #pragma unroll
  for (int off = 32; off; off >>= 1) s += __shfl_xor(s, off);
  if (lane == 0) out[b] = s + bout[0];
}

// W1 [429,1024] -> w1bt [1024,448] bf16 K-major permuted+padded;
// W2 [1024,1024] -> w2bt bf16 transposed.  One kernel.
__global__ void prep_w(const float* __restrict__ W1, const float* __restrict__ W2,
                       u16* __restrict__ w1bt, u16* __restrict__ w2bt) {
  int t = blockIdx.x * blockDim.x + threadIdx.x;
  if (t < H_ * KP1_) {
    int n = t / KP1_, e = t % KP1_;
    float v = 0.f;
    if (e < D_) {
      int d = (e < 416) ? (13 + e) : (e - 416);
      v = W1[(size_t)d * H_ + n];
    }
    w1bt[t] = f2bf_bits(v);
  } else {
    int t2 = t - H_ * KP1_;
    if (t2 < H_ * H_) {
      int n = t2 / H_, k = t2 % H_;
      w2bt[t2] = f2bf_bits(W2[(size_t)k * H_ + n]);
    }
  }
}

// 256x256 tile, BK=32, 8 waves (2x4), 4-buffer LDS ring, counted vmcnt.
// MODE 0: C = bf16(relu(A@BT^T + bias)).  MODE 1: out[row] += sum_col relu(.)*Wout[col].
template<int MODE>
__global__ __launch_bounds__(512, 2) void gemm256(
    const u16* __restrict__ A, const u16* __restrict__ BT,
    const float* __restrict__ bias, u16* __restrict__ C,
    const float* __restrict__ Wout, float* __restrict__ out,
    int N, int K) {
  __shared__ __align__(16) u16 As[4][256 * 32];
  __shared__ __align__(16) u16 Bs[4][256 * 32];
  const int nbx = N >> 8;
  const int bx = blockIdx.x % nbx;
  const int by = blockIdx.x / nbx;
  const int tid = threadIdx.x;
  const int w = tid >> 6, l = tid & 63;
  const int wr = w >> 2, wc = w & 3;
  const int nkt = K >> 5;

  const int srow = l >> 2;
  const int schunk = (l & 3) ^ ((l >> 3) & 3);
  const u16* gA = A  + (size_t)(by * 256 + w * 16 + srow) * K + schunk * 8;
  const u16* gB = BT + (size_t)(bx * 256 + w * 16 + srow) * K + schunk * 8;
  const int ldsoff = w * 16 * 32;   // u16 units

  auto stage = [&](int t) {
    const int buf = t & 3;
    const u16* a = gA + t * 32;
    const u16* b = gB + t * 32;
    #pragma unroll
    for (int i = 0; i < 2; ++i)
      __builtin_amdgcn_global_load_lds(
          (const __attribute__((address_space(1))) void*)(a + (size_t)i * 128 * K),
          (__attribute__((address_space(3))) void*)&As[buf][ldsoff + i * 128 * 32], 16, 0, 0);
    #pragma unroll
    for (int i = 0; i < 2; ++i)
      __builtin_amdgcn_global_load_lds(
          (const __attribute__((address_space(1))) void*)(b + (size_t)i * 128 * K),
          (__attribute__((address_space(3))) void*)&Bs[buf][ldsoff + i * 128 * 32], 16, 0, 0);
  };

  stage(0); stage(1); stage(2);

  const int fr = l & 15;
  const int fs = ((l >> 4) ^ ((fr >> 1) & 3)) << 4;
  const int aoff = (wr * 128 + fr) * 64 + fs;
  const int boff = (wc * 64 + fr) * 64 + fs;

  f32x4 acc[8][4] = {};

  asm volatile("s_waitcnt vmcnt(8)" ::: "memory");
  __builtin_amdgcn_s_barrier();

  for (int t = 0; t < nkt; ++t) {
    if (t + 3 < nkt) stage(t + 3);
    const char* Ab = (const char*)&As[t & 3][0];
    const char* Bb = (const char*)&Bs[t & 3][0];
    bf16x8 af[8], bf[4];
    #pragma unroll
    for (int m = 0; m < 8; ++m) af[m] = *(const bf16x8*)(Ab + aoff + m * 1024);
    #pragma unroll
    for (int n = 0; n < 4; ++n) bf[n] = *(const bf16x8*)(Bb + boff + n * 1024);
    __builtin_amdgcn_s_setprio(1);
    #pragma unroll
    for (int m = 0; m < 8; ++m)
      #pragma unroll
      for (int n = 0; n < 4; ++n)
        acc[m][n] = __builtin_amdgcn_mfma_f32_16x16x32_bf16(af[m], bf[n], acc[m][n], 0, 0, 0);
    __builtin_amdgcn_s_setprio(0);
    if (t + 3 < nkt)      asm volatile("s_waitcnt vmcnt(8)" ::: "memory");
    else if (t + 2 < nkt) asm volatile("s_waitcnt vmcnt(4)" ::: "memory");
    else if (t + 1 < nkt) asm volatile("s_waitcnt vmcnt(0)" ::: "memory");
    if (t + 1 < nkt) __builtin_amdgcn_s_barrier();
  }

  const int g4 = l >> 4;
  const int ccol0 = bx * 256 + wc * 64;
  const int row0 = by * 256 + wr * 128 + g4 * 4;
  if (MODE == 0) {
    #pragma unroll
    for (int n = 0; n < 4; ++n) {
      int col = ccol0 + n * 16 + fr;
      float bv = bias[col];
      #pragma unroll
      for (int m = 0; m < 8; ++m)
        #pragma unroll
        for (int r = 0; r < 4; ++r) {
          float v = fmaxf(acc[m][n][r] + bv, 0.f);
          C[(size_t)(row0 + m * 16 + r) * N + col] = f2bf_bits(v);
        }
    }
  } else {
    float bv[4], wv[4];
    #pragma unroll
    for (int n = 0; n < 4; ++n) {
      int col = ccol0 + n * 16 + fr;
      bv[n] = bias[col]; wv[n] = Wout[col];
    }
    #pragma unroll
    for (int m = 0; m < 8; ++m)
      #pragma unroll
      for (int r = 0; r < 4; ++r) {
        float s = 0.f;
        #pragma unroll
        for (int n = 0; n < 4; ++n) {
          float v = fmaxf(acc[m][n][r] + bv[n], 0.f);
          s = fmaf(v, wv[n], s);
        }
        s += __shfl_xor(s, 1); s += __shfl_xor(s, 2);
        s += __shfl_xor(s, 4); s += __shfl_xor(s, 8);
        if (fr == 0) atomicAdd(out + row0 + m * 16 + r, s);
      }
  }
}

extern "C" void kernel_launch(void* const* d_in, const int* in_sizes, int n_in,
                              void* d_out, int out_size, void* d_ws, size_t ws_size,
                              hipStream_t stream) {
  const int*   Xi   = (const int*)d_in[0];
  const float* Xv   = (const float*)d_in[1];
  const float* emb  = (const float*)d_in[2];
  const float* cw   = (const float*)d_in[3];
  const float* cb   = (const float*)d_in[4];
  const float* W1   = (const float*)d_in[5];
  const float* b1   = (const float*)d_in[6];
  const float* W2   = (const float*)d_in[7];
  const float* b2   = (const float*)d_in[8];
  const float* Wout = (const float*)d_in[9];
  const float* bout = (const float*)d_in[10];
  float* out = (float*)d_out;

  char* ws = (char*)d_ws;
  size_t off = 0;
  auto alloc = [&](size_t bytes) {
    void* p = ws + off; off += (bytes + 255) & ~(size_t)255; return p;
  };
  u16* x0b  = (u16*)alloc((size_t)B_ * KP1_ * 2);
  u16* w1bt = (u16*)alloc((size_t)H_ * KP1_ * 2);
  u16* w2bt = (u16*)alloc((size_t)H_ * H_ * 2);
  u16* h1   = (u16*)alloc((size_t)B_ * H_ * 2);

  hipLaunchKernelGGL(build_cross, dim3(B_ / 4), dim3(256), 0, stream,
                     Xi, Xv, emb, cw, cb, Wout, bout, x0b, out);
  hipLaunchKernelGGL(prep_w, dim3((H_ * KP1_ + H_ * H_ + 255) / 256), dim3(256), 0, stream,
                     W1, W2, w1bt, w2bt);
  hipLaunchKernelGGL((gemm256<0>), dim3((B_ / 256) * (H_ / 256)), dim3(512), 0, stream,
                     x0b, w1bt, b1, h1, nullptr, nullptr, H_, KP1_);
  hipLaunchKernelGGL((gemm256<1>), dim3((B_ / 256) * (H_ / 256)), dim3(512), 0, stream,
                     h1, w2bt, b2, nullptr, Wout, out, H_, H_);
}

// Round 5
// 107.246 us; speedup vs baseline: 1.4141x; 1.0642x over previous
//
#include <hip/hip_runtime.h>
#include <hip/hip_bf16.h>

#define B_   16384
#define F_   26
#define N_   100000
#define M_   16
#define NUM_ 13
#define D_   429
#define KP1_ 448     // padded K for GEMM1 (bf16 operand), multiple of 32
#define L_   6
#define H_   1024

typedef unsigned short u16;
typedef __bf16 bf16x8 __attribute__((ext_vector_type(8)));
typedef float  f32x4  __attribute__((ext_vector_type(4)));

__device__ __forceinline__ u16 f2bf_bits(float f) {
  union { float f; unsigned u; } x; x.f = f;
  unsigned r = x.u + 0x7FFFu + ((x.u >> 16) & 1u);   // RNE
  return (u16)(r >> 16);
}

// Fused front kernel.
// Blocks [0, B_/4): embedding gather -> x0 (regs) -> bf16 x0 row -> CrossNet
//                   -> out[b] = x . Wout[1024+d] + bout
// Blocks [B_/4, ...): weight prep (W1 -> w1bt permuted+padded K-major bf16;
//                     W2 -> w2bt transposed bf16)
// x0 permuted layout: [ g(0..415) | Xv(416..428) | zeros(429..447) ]
//   orig d<13 -> 416+d ; d>=13 -> d-13
__global__ __launch_bounds__(256) void fused_front(
    const int* __restrict__ Xi, const float* __restrict__ Xv,
    const float* __restrict__ emb,
    const float* __restrict__ cw, const float* __restrict__ cb,
    const float* __restrict__ Wout, const float* __restrict__ bout,
    const float* __restrict__ W1, const float* __restrict__ W2,
    u16* __restrict__ x0b, u16* __restrict__ w1bt, u16* __restrict__ w2bt,
    float* __restrict__ out) {
  __shared__ u16 sbuf[4][KP1_];
  const int blk = blockIdx.x;
  if (blk < B_ / 4) {
    const int w = threadIdx.x >> 6, lane = threadIdx.x & 63;
    const int b = blk * 4 + w;
    const int* xi = Xi + b * F_;

    float x0r[7];
    #pragma unroll
    for (int i = 0; i < 7; ++i) {
      int e = i * 64 + lane;
      float v = 0.f;
      if (e < 416) {
        int f = e >> 4;
        int idx = xi[f];
        v = emb[((size_t)f * N_ + idx) * M_ + (e & 15)];
      } else if (e < D_) {
        v = Xv[b * NUM_ + (e - 416)];
      }
      x0r[i] = v;
      sbuf[w][e] = f2bf_bits(v);
    }

    float xr[7];
    #pragma unroll
    for (int i = 0; i < 7; ++i) xr[i] = x0r[i];
    for (int l = 0; l < L_; ++l) {
      float wl[7], bl[7];
      #pragma unroll
      for (int i = 0; i < 7; ++i) {
        int e = i * 64 + lane;
        if (e < D_) {
          int d = (e < 416) ? (13 + e) : (e - 416);
          wl[i] = cw[l * D_ + d]; bl[i] = cb[l * D_ + d];
        } else { wl[i] = 0.f; bl[i] = 0.f; }
      }
      float s = 0.f;
      #pragma unroll
      for (int i = 0; i < 7; ++i) s += xr[i] * wl[i];
      #pragma unroll
      for (int off = 32; off; off >>= 1) s += __shfl_xor(s, off);
      #pragma unroll
      for (int i = 0; i < 7; ++i) xr[i] = x0r[i] * s + bl[i] + xr[i];
    }

    __syncthreads();
    if (lane < 56)
      ((uint4*)(x0b + (size_t)b * KP1_))[lane] = ((const uint4*)sbuf[w])[lane];

    float s = 0.f;
    #pragma unroll
    for (int i = 0; i < 7; ++i) {
      int e = i * 64 + lane;
      if (e < D_) {
        int d = (e < 416) ? (13 + e) : (e - 416);
        s += xr[i] * Wout[H_ + d];
      }
    }
    #pragma unroll
    for (int off = 32; off; off >>= 1) s += __shfl_xor(s, off);
    if (lane == 0) out[b] = s + bout[0];
  } else {
    int t = (blk - B_ / 4) * 256 + threadIdx.x;
    if (t < H_ * KP1_) {
      int n = t / KP1_, e = t % KP1_;
      float v = 0.f;
      if (e < D_) {
        int d = (e < 416) ? (13 + e) : (e - 416);
        v = W1[(size_t)d * H_ + n];
      }
      w1bt[t] = f2bf_bits(v);
    } else {
      int t2 = t - H_ * KP1_;
      if (t2 < H_ * H_) {
        int n = t2 / H_, k = t2 % H_;
        w2bt[t2] = f2bf_bits(W2[(size_t)k * H_ + n]);
      }
    }
  }
}

// 256x256 tile, BK=32, 8 waves (2x4), 4-buffer LDS ring, counted vmcnt,
// register-double-buffered fragments.
// Invariant at top of iter t: buffers t&3 and (t+1)&3 complete & published
// (established by end-of-prev-iter vmcnt covering stage(t+1) THEN barrier),
// so read_frags(t+1) inside iter t is cross-wave race-free.
// MODE 0: C = bf16(relu(A@BT^T + bias)).  MODE 1: out[row] += sum_col relu(.)*Wout[col].
template<int MODE>
__global__ __launch_bounds__(512, 2) void gemm256(
    const u16* __restrict__ A, const u16* __restrict__ BT,
    const float* __restrict__ bias, u16* __restrict__ C,
    const float* __restrict__ Wout, float* __restrict__ out,
    int N, int K) {
  __shared__ __align__(16) u16 As[4][256 * 32];
  __shared__ __align__(16) u16 Bs[4][256 * 32];
  const int nbx = N >> 8;
  // T1: XCD-contiguous remap (grid is a multiple of 8)
  const int cpx = gridDim.x >> 3;
  const int swz = (blockIdx.x & 7) * cpx + (blockIdx.x >> 3);
  const int bx = swz % nbx;
  const int by = swz / nbx;
  const int tid = threadIdx.x;
  const int w = tid >> 6, l = tid & 63;
  const int wr = w >> 2, wc = w & 3;
  const int nkt = K >> 5;   // 14 for K=448, 32 for K=1024 (both even)

  const int srow = l >> 2;
  const int schunk = (l & 3) ^ ((l >> 3) & 3);
  const u16* gA = A  + (size_t)(by * 256 + w * 16 + srow) * K + schunk * 8;
  const u16* gB = BT + (size_t)(bx * 256 + w * 16 + srow) * K + schunk * 8;
  const int ldsoff = w * 16 * 32;   // u16 units

  auto stage = [&](int t) {
    const int buf = t & 3;
    const u16* a = gA + t * 32;
    const u16* b = gB + t * 32;
    #pragma unroll
    for (int i = 0; i < 2; ++i)
      __builtin_amdgcn_global_load_lds(
          (const __attribute__((address_space(1))) void*)(a + (size_t)i * 128 * K),
          (__attribute__((address_space(3))) void*)&As[buf][ldsoff + i * 128 * 32], 16, 0, 0);
    #pragma unroll
    for (int i = 0; i < 2; ++i)
      __builtin_amdgcn_global_load_lds(
          (const __attribute__((address_space(1))) void*)(b + (size_t)i * 128 * K),
          (__attribute__((address_space(3))) void*)&Bs[buf][ldsoff + i * 128 * 32], 16, 0, 0);
  };

  const int fr = l & 15;
  const int fs = ((l >> 4) ^ ((fr >> 1) & 3)) << 4;
  const int aoff = (wr * 128 + fr) * 64 + fs;
  const int boff = (wc * 64 + fr) * 64 + fs;

  auto read_frags = [&](int tt, bf16x8 (&af)[8], bf16x8 (&bf)[4]) {
    const char* Ab = (const char*)&As[tt & 3][0];
    const char* Bb = (const char*)&Bs[tt & 3][0];
    #pragma unroll
    for (int m = 0; m < 8; ++m) af[m] = *(const bf16x8*)(Ab + aoff + m * 1024);
    #pragma unroll
    for (int n = 0; n < 4; ++n) bf[n] = *(const bf16x8*)(Bb + boff + n * 1024);
  };

  f32x4 acc[8][4] = {};
  auto mfma_all = [&](bf16x8 (&af)[8], bf16x8 (&bf)[4]) {
    __builtin_amdgcn_s_setprio(1);
    #pragma unroll
    for (int m = 0; m < 8; ++m)
      #pragma unroll
      for (int n = 0; n < 4; ++n)
        acc[m][n] = __builtin_amdgcn_mfma_f32_16x16x32_bf16(af[m], bf[n], acc[m][n], 0, 0, 0);
    __builtin_amdgcn_s_setprio(0);
  };

  stage(0); stage(1); stage(2);
  asm volatile("s_waitcnt vmcnt(4)" ::: "memory");   // stages 0,1 landed (this wave)
  __builtin_amdgcn_s_barrier();                      // ...published by all waves
  bf16x8 afA[8], bfA[4], afB[8], bfB[4];
  read_frags(0, afA, bfA);

  for (int t = 0; t < nkt; t += 2) {
    // ---- iter t: compute frag set A(t); preload frag set B(t+1)
    if (t + 3 < nkt) stage(t + 3);                   // writes buf (t-1)&3: WAR-safe
    if (t + 1 < nkt) read_frags(t + 1, afB, bfB);    // buf (t+1)&3 complete per invariant
    mfma_all(afA, bfA);
    if (t + 2 < nkt) {                               // publish buf (t+2)&3 for next iter
      if (t + 3 < nkt) asm volatile("s_waitcnt vmcnt(4)" ::: "memory");
      else             asm volatile("s_waitcnt vmcnt(0)" ::: "memory");
      __builtin_amdgcn_s_barrier();
    }
    // ---- iter u = t+1: compute frag set B; preload frag set A(t+2)
    const int u = t + 1;
    if (u < nkt) {
      if (u + 3 < nkt) stage(u + 3);
      if (u + 1 < nkt) read_frags(u + 1, afA, bfA);
      mfma_all(afB, bfB);
      if (u + 2 < nkt) {
        if (u + 3 < nkt) asm volatile("s_waitcnt vmcnt(4)" ::: "memory");
        else             asm volatile("s_waitcnt vmcnt(0)" ::: "memory");
        __builtin_amdgcn_s_barrier();
      }
    }
  }

  const int g4 = l >> 4;
  const int ccol0 = bx * 256 + wc * 64;
  const int row0 = by * 256 + wr * 128 + g4 * 4;
  if (MODE == 0) {
    #pragma unroll
    for (int n = 0; n < 4; ++n) {
      int col = ccol0 + n * 16 + fr;
      float bv = bias[col];
      #pragma unroll
      for (int m = 0; m < 8; ++m)
        #pragma unroll
        for (int r = 0; r < 4; ++r) {
          float v = fmaxf(acc[m][n][r] + bv, 0.f);
          C[(size_t)(row0 + m * 16 + r) * N + col] = f2bf_bits(v);
        }
    }
  } else {
    float bv[4], wv[4];
    #pragma unroll
    for (int n = 0; n < 4; ++n) {
      int col = ccol0 + n * 16 + fr;
      bv[n] = bias[col]; wv[n] = Wout[col];
    }
    #pragma unroll
    for (int m = 0; m < 8; ++m)
      #pragma unroll
      for (int r = 0; r < 4; ++r) {
        float s = 0.f;
        #pragma unroll
        for (int n = 0; n < 4; ++n) {
          float v = fmaxf(acc[m][n][r] + bv[n], 0.f);
          s = fmaf(v, wv[n], s);
        }
        s += __shfl_xor(s, 1); s += __shfl_xor(s, 2);
        s += __shfl_xor(s, 4); s += __shfl_xor(s, 8);
        if (fr == 0) atomicAdd(out + row0 + m * 16 + r, s);
      }
  }
}

extern "C" void kernel_launch(void* const* d_in, const int* in_sizes, int n_in,
                              void* d_out, int out_size, void* d_ws, size_t ws_size,
                              hipStream_t stream) {
  const int*   Xi   = (const int*)d_in[0];
  const float* Xv   = (const float*)d_in[1];
  const float* emb  = (const float*)d_in[2];
  const float* cw   = (const float*)d_in[3];
  const float* cb   = (const float*)d_in[4];
  const float* W1   = (const float*)d_in[5];
  const float* b1   = (const float*)d_in[6];
  const float* W2   = (const float*)d_in[7];
  const float* b2   = (const float*)d_in[8];
  const float* Wout = (const float*)d_in[9];
  const float* bout = (const float*)d_in[10];
  float* out = (float*)d_out;

  char* ws = (char*)d_ws;
  size_t off = 0;
  auto alloc = [&](size_t bytes) {
    void* p = ws + off; off += (bytes + 255) & ~(size_t)255; return p;
  };
  u16* x0b  = (u16*)alloc((size_t)B_ * KP1_ * 2);
  u16* w1bt = (u16*)alloc((size_t)H_ * KP1_ * 2);
  u16* w2bt = (u16*)alloc((size_t)H_ * H_ * 2);
  u16* h1   = (u16*)alloc((size_t)B_ * H_ * 2);

  const int prep_blocks = (H_ * KP1_ + H_ * H_) / 256;   // 5888
  hipLaunchKernelGGL(fused_front, dim3(B_ / 4 + prep_blocks), dim3(256), 0, stream,
                     Xi, Xv, emb, cw, cb, Wout, bout, W1, W2, x0b, w1bt, w2bt, out);
  hipLaunchKernelGGL((gemm256<0>), dim3((B_ / 256) * (H_ / 256)), dim3(512), 0, stream,
                     x0b, w1bt, b1, h1, nullptr, nullptr, H_, KP1_);
  hipLaunchKernelGGL((gemm256<1>), dim3((B_ / 256) * (H_ / 256)), dim3(512), 0, stream,
                     h1, w2bt, b2, nullptr, Wout, out, H_, H_);
}

// Round 6
// 98.806 us; speedup vs baseline: 1.5349x; 1.0854x over previous
//
#include <hip/hip_runtime.h>
#include <hip/hip_bf16.h>

#define B_   16384
#define F_   26
#define N_   100000
#define M_   16
#define NUM_ 13
#define D_   429
#define KP1_ 448     // padded K for GEMM1 (bf16 operand), multiple of 64
#define L_   6
#define H_   1024

typedef unsigned short u16;
typedef __bf16 bf16x8 __attribute__((ext_vector_type(8)));
typedef float  f32x4  __attribute__((ext_vector_type(4)));

__device__ __forceinline__ u16 f2bf_bits(float f) {
  union { float f; unsigned u; } x; x.f = f;
  unsigned r = x.u + 0x7FFFu + ((x.u >> 16) & 1u);   // RNE
  return (u16)(r >> 16);
}

// Fused front kernel.
// Blocks [0, B_/4): embedding gather -> x0 (regs) -> bf16 x0 row -> CrossNet
//                   -> out[b] = x . Wout[1024+d] + bout
// Blocks [B_/4, ...): weight prep (W1 -> w1bt permuted+padded K-major bf16;
//                     W2 -> w2bt transposed bf16)
// x0 permuted layout: [ g(0..415) | Xv(416..428) | zeros(429..447) ]
//   orig d<13 -> 416+d ; d>=13 -> d-13
__global__ __launch_bounds__(256) void fused_front(
    const int* __restrict__ Xi, const float* __restrict__ Xv,
    const float* __restrict__ emb,
    const float* __restrict__ cw, const float* __restrict__ cb,
    const float* __restrict__ Wout, const float* __restrict__ bout,
    const float* __restrict__ W1, const float* __restrict__ W2,
    u16* __restrict__ x0b, u16* __restrict__ w1bt, u16* __restrict__ w2bt,
    float* __restrict__ out) {
  __shared__ u16 sbuf[4][KP1_];
  const int blk = blockIdx.x;
  if (blk < B_ / 4) {
    const int w = threadIdx.x >> 6, lane = threadIdx.x & 63;
    const int b = blk * 4 + w;
    const int* xi = Xi + b * F_;

    float x0r[7];
    #pragma unroll
    for (int i = 0; i < 7; ++i) {
      int e = i * 64 + lane;
      float v = 0.f;
      if (e < 416) {
        int f = e >> 4;
        int idx = xi[f];
        v = emb[((size_t)f * N_ + idx) * M_ + (e & 15)];
      } else if (e < D_) {
        v = Xv[b * NUM_ + (e - 416)];
      }
      x0r[i] = v;
      sbuf[w][e] = f2bf_bits(v);
    }

    float xr[7];
    #pragma unroll
    for (int i = 0; i < 7; ++i) xr[i] = x0r[i];
    for (int l = 0; l < L_; ++l) {
      float wl[7], bl[7];
      #pragma unroll
      for (int i = 0; i < 7; ++i) {
        int e = i * 64 + lane;
        if (e < D_) {
          int d = (e < 416) ? (13 + e) : (e - 416);
          wl[i] = cw[l * D_ + d]; bl[i] = cb[l * D_ + d];
        } else { wl[i] = 0.f; bl[i] = 0.f; }
      }
      float s = 0.f;
      #pragma unroll
      for (int i = 0; i < 7; ++i) s += xr[i] * wl[i];
      #pragma unroll
      for (int off = 32; off; off >>= 1) s += __shfl_xor(s, off);
      #pragma unroll
      for (int i = 0; i < 7; ++i) xr[i] = x0r[i] * s + bl[i] + xr[i];
    }

    __syncthreads();
    if (lane < 56)
      ((uint4*)(x0b + (size_t)b * KP1_))[lane] = ((const uint4*)sbuf[w])[lane];

    float s = 0.f;
    #pragma unroll
    for (int i = 0; i < 7; ++i) {
      int e = i * 64 + lane;
      if (e < D_) {
        int d = (e < 416) ? (13 + e) : (e - 416);
        s += xr[i] * Wout[H_ + d];
      }
    }
    #pragma unroll
    for (int off = 32; off; off >>= 1) s += __shfl_xor(s, off);
    if (lane == 0) out[b] = s + bout[0];
  } else {
    int t = (blk - B_ / 4) * 256 + threadIdx.x;
    if (t < H_ * KP1_) {
      int n = t / KP1_, e = t % KP1_;
      float v = 0.f;
      if (e < D_) {
        int d = (e < 416) ? (13 + e) : (e - 416);
        v = W1[(size_t)d * H_ + n];
      }
      w1bt[t] = f2bf_bits(v);
    } else {
      int t2 = t - H_ * KP1_;
      if (t2 < H_ * H_) {
        int n = t2 / H_, k = t2 % H_;
        w2bt[t2] = f2bf_bits(W2[(size_t)k * H_ + n]);
      }
    }
  }
}

// 256x256 tile, BK=64, 8 waves (2x4), 2-buffer LDS double-buffer,
// m201-style 4-phase interleave per K-tile, T2 st-swizzle
// (byte ^= (row&7)<<4; inverse-swizzled global source, linear LDS dest),
// counted-vmcnt discipline (drain point >= 2 phases after last issue),
// T1 XCD-contiguous block swizzle, T5 setprio around MFMA clusters.
// MODE 0: C = bf16(relu(A@BT^T + bias)).  MODE 1: out[row] += sum_col relu(.)*Wout[col].
template<int MODE>
__global__ __launch_bounds__(512, 2) void gemm256(
    const u16* __restrict__ A, const u16* __restrict__ BT,
    const float* __restrict__ bias, u16* __restrict__ C,
    const float* __restrict__ Wout, float* __restrict__ out,
    int N, int K) {
  __shared__ __align__(16) u16 As[2][256 * 64];
  __shared__ __align__(16) u16 Bs[2][256 * 64];
  const int nbx = N >> 8;
  const int cpx = gridDim.x >> 3;
  const int swz = (blockIdx.x & 7) * cpx + (blockIdx.x >> 3);
  const int bx = swz % nbx;
  const int by = swz / nbx;
  const int tid = threadIdx.x;
  const int l = tid & 63;
  const int w = tid >> 6;
  const int wr = w >> 2, wc = w & 3;
  const int nkt = K >> 6;   // 7 for K=448, 16 for K=1024

  // ---- staging (inverse-swizzled source, linear LDS dest) ----
  // thread covers rows r0 + i*64 (i=0..3), 16 B chunk; LDS byte = i*8192 + tid*16
  // LDS(row, c') holds global (row, c'^((row&7)<<4))
  const int r0 = tid >> 3;
  const int scol = ((tid & 7) ^ (r0 & 7)) << 4;   // source col bytes within tile
  const char* gA = (const char*)(A + (size_t)(by * 256 + r0) * K) + scol;
  const char* gB = (const char*)(BT + (size_t)(bx * 256 + r0) * K) + scol;
  const size_t rowstep = (size_t)64 * K * 2;
  const int dst0 = tid * 8;   // u16 units

  auto stageA = [&](int t) {
    const int buf = t & 1;
    const char* src = gA + (size_t)t * 128;
    #pragma unroll
    for (int i = 0; i < 4; ++i)
      __builtin_amdgcn_global_load_lds(
          (const __attribute__((address_space(1))) void*)(src + i * rowstep),
          (__attribute__((address_space(3))) void*)&As[buf][dst0 + i * 4096], 16, 0, 0);
  };
  auto stageB = [&](int t) {
    const int buf = t & 1;
    const char* src = gB + (size_t)t * 128;
    #pragma unroll
    for (int i = 0; i < 4; ++i)
      __builtin_amdgcn_global_load_lds(
          (const __attribute__((address_space(1))) void*)(src + i * rowstep),
          (__attribute__((address_space(3))) void*)&Bs[buf][dst0 + i * 4096], 16, 0, 0);
  };

  // ---- fragment read offsets (bytes), matching swizzle on ds_read ----
  const int fr = l & 15, g = l >> 4;
  const int csw = (g * 16) ^ ((fr & 7) << 4);          // kh0; kh1 = ^64
  const int aoff = (wr * 128 + fr) * 128 + csw;
  const int boff = (wc * 64 + fr) * 128 + csw;

  f32x4 acc[8][4] = {};

  stageA(0); stageB(0);
  asm volatile("s_waitcnt vmcnt(0)" ::: "memory");
  __builtin_amdgcn_s_barrier();

  for (int t = 0; t < nkt; ++t) {
    const char* Ab = (const char*)&As[t & 1][0];
    const char* Bb = (const char*)&Bs[t & 1][0];
    const bool pre = (t + 1 < nkt);
    bf16x8 af[4], bf[4];

    // ---- P0: frags (m0-3, kh0) + B(kh0); issue stage A(t+1)
    #pragma unroll
    for (int m = 0; m < 4; ++m) af[m] = *(const bf16x8*)(Ab + aoff + m * 2048);
    #pragma unroll
    for (int n = 0; n < 4; ++n) bf[n] = *(const bf16x8*)(Bb + boff + n * 2048);
    if (pre) stageA(t + 1);
    __builtin_amdgcn_sched_barrier(0);
    __builtin_amdgcn_s_barrier();
    __builtin_amdgcn_s_setprio(1);
    #pragma unroll
    for (int m = 0; m < 4; ++m)
      #pragma unroll
      for (int n = 0; n < 4; ++n)
        acc[m][n] = __builtin_amdgcn_mfma_f32_16x16x32_bf16(af[m], bf[n], acc[m][n], 0, 0, 0);
    __builtin_amdgcn_s_setprio(0);
    __builtin_amdgcn_s_barrier();

    // ---- P1: frags (m4-7, kh0); issue stage B(t+1)
    #pragma unroll
    for (int m = 0; m < 4; ++m) af[m] = *(const bf16x8*)(Ab + aoff + (m + 4) * 2048);
    if (pre) stageB(t + 1);
    __builtin_amdgcn_sched_barrier(0);
    __builtin_amdgcn_s_barrier();
    __builtin_amdgcn_s_setprio(1);
    #pragma unroll
    for (int m = 0; m < 4; ++m)
      #pragma unroll
      for (int n = 0; n < 4; ++n)
        acc[m + 4][n] = __builtin_amdgcn_mfma_f32_16x16x32_bf16(af[m], bf[n], acc[m + 4][n], 0, 0, 0);
    __builtin_amdgcn_s_setprio(0);
    __builtin_amdgcn_s_barrier();

    // ---- P2: frags (m0-3, kh1) + B(kh1)
    #pragma unroll
    for (int m = 0; m < 4; ++m) af[m] = *(const bf16x8*)(Ab + (aoff ^ 64) + m * 2048);
    #pragma unroll
    for (int n = 0; n < 4; ++n) bf[n] = *(const bf16x8*)(Bb + (boff ^ 64) + n * 2048);
    __builtin_amdgcn_sched_barrier(0);
    __builtin_amdgcn_s_barrier();
    __builtin_amdgcn_s_setprio(1);
    #pragma unroll
    for (int m = 0; m < 4; ++m)
      #pragma unroll
      for (int n = 0; n < 4; ++n)
        acc[m][n] = __builtin_amdgcn_mfma_f32_16x16x32_bf16(af[m], bf[n], acc[m][n], 0, 0, 0);
    __builtin_amdgcn_s_setprio(0);
    __builtin_amdgcn_s_barrier();

    // ---- P3: frags (m4-7, kh1); publish staged tile t+1 (vmcnt BEFORE barrier)
    #pragma unroll
    for (int m = 0; m < 4; ++m) af[m] = *(const bf16x8*)(Ab + (aoff ^ 64) + (m + 4) * 2048);
    __builtin_amdgcn_sched_barrier(0);
    __builtin_amdgcn_s_barrier();
    __builtin_amdgcn_s_setprio(1);
    #pragma unroll
    for (int m = 0; m < 4; ++m)
      #pragma unroll
      for (int n = 0; n < 4; ++n)
        acc[m + 4][n] = __builtin_amdgcn_mfma_f32_16x16x32_bf16(af[m], bf[n], acc[m + 4][n], 0, 0, 0);
    __builtin_amdgcn_s_setprio(0);
    if (pre) asm volatile("s_waitcnt vmcnt(0)" ::: "memory");
    __builtin_amdgcn_s_barrier();
  }

  const int ccol0 = bx * 256 + wc * 64;
  const int row0 = by * 256 + wr * 128 + g * 4;
  if (MODE == 0) {
    #pragma unroll
    for (int n = 0; n < 4; ++n) {
      int col = ccol0 + n * 16 + fr;
      float bv = bias[col];
      #pragma unroll
      for (int m = 0; m < 8; ++m)
        #pragma unroll
        for (int r = 0; r < 4; ++r) {
          float v = fmaxf(acc[m][n][r] + bv, 0.f);
          C[(size_t)(row0 + m * 16 + r) * N + col] = f2bf_bits(v);
        }
    }
  } else {
    float bv[4], wv[4];
    #pragma unroll
    for (int n = 0; n < 4; ++n) {
      int col = ccol0 + n * 16 + fr;
      bv[n] = bias[col]; wv[n] = Wout[col];
    }
    #pragma unroll
    for (int m = 0; m < 8; ++m)
      #pragma unroll
      for (int r = 0; r < 4; ++r) {
        float s = 0.f;
        #pragma unroll
        for (int n = 0; n < 4; ++n) {
          float v = fmaxf(acc[m][n][r] + bv[n], 0.f);
          s = fmaf(v, wv[n], s);
        }
        s += __shfl_xor(s, 1); s += __shfl_xor(s, 2);
        s += __shfl_xor(s, 4); s += __shfl_xor(s, 8);
        if (fr == 0) atomicAdd(out + row0 + m * 16 + r, s);
      }
  }
}

extern "C" void kernel_launch(void* const* d_in, const int* in_sizes, int n_in,
                              void* d_out, int out_size, void* d_ws, size_t ws_size,
                              hipStream_t stream) {
  const int*   Xi   = (const int*)d_in[0];
  const float* Xv   = (const float*)d_in[1];
  const float* emb  = (const float*)d_in[2];
  const float* cw   = (const float*)d_in[3];
  const float* cb   = (const float*)d_in[4];
  const float* W1   = (const float*)d_in[5];
  const float* b1   = (const float*)d_in[6];
  const float* W2   = (const float*)d_in[7];
  const float* b2   = (const float*)d_in[8];
  const float* Wout = (const float*)d_in[9];
  const float* bout = (const float*)d_in[10];
  float* out = (float*)d_out;

  char* ws = (char*)d_ws;
  size_t off = 0;
  auto alloc = [&](size_t bytes) {
    void* p = ws + off; off += (bytes + 255) & ~(size_t)255; return p;
  };
  u16* x0b  = (u16*)alloc((size_t)B_ * KP1_ * 2);
  u16* w1bt = (u16*)alloc((size_t)H_ * KP1_ * 2);
  u16* w2bt = (u16*)alloc((size_t)H_ * H_ * 2);
  u16* h1   = (u16*)alloc((size_t)B_ * H_ * 2);

  const int prep_blocks = (H_ * KP1_ + H_ * H_) / 256;   // 5888
  hipLaunchKernelGGL(fused_front, dim3(B_ / 4 + prep_blocks), dim3(256), 0, stream,
                     Xi, Xv, emb, cw, cb, Wout, bout, W1, W2, x0b, w1bt, w2bt, out);
  hipLaunchKernelGGL((gemm256<0>), dim3((B_ / 256) * (H_ / 256)), dim3(512), 0, stream,
                     x0b, w1bt, b1, h1, nullptr, nullptr, H_, KP1_);
  hipLaunchKernelGGL((gemm256<1>), dim3((B_ / 256) * (H_ / 256)), dim3(512), 0, stream,
                     h1, w2bt, b2, nullptr, Wout, out, H_, H_);
}

// Round 7
// 94.631 us; speedup vs baseline: 1.6026x; 1.0441x over previous
//
#include <hip/hip_runtime.h>
#include <hip/hip_bf16.h>

#define B_   16384
#define F_   26
#define N_   100000
#define M_   16
#define NUM_ 13
#define D_   429
#define KP1_ 512     // padded K for GEMM1 (bf16 operand), multiple of 64, even K-tiles
#define L_   6
#define H_   1024

typedef unsigned short u16;
typedef __bf16 bf16x8 __attribute__((ext_vector_type(8)));
typedef float  f32x4  __attribute__((ext_vector_type(4)));

__device__ __forceinline__ u16 f2bf_bits(float f) {
  union { float f; unsigned u; } x; x.f = f;
  unsigned r = x.u + 0x7FFFu + ((x.u >> 16) & 1u);   // RNE
  return (u16)(r >> 16);
}

// Fused front kernel.
// Blocks [0, 4096): embedding gather -> x0 (regs) -> bf16 x0 row -> CrossNet
//                   -> out[b] = x . Wout[1024+d] + bout
// Blocks [4096, 4096+112): W1 -> w1bt [1024][512] bf16 (permuted e-space), LDS-tiled transpose
// Blocks [4096+112, 4096+368): W2 -> w2bt [1024][1024] bf16 transposed, LDS-tiled
// x0 permuted layout: [ g(0..415) | Xv(416..428) | zeros(429..511) ]
//   orig d<13 -> 416+d ; d>=13 -> d-13
__global__ __launch_bounds__(256) void fused_front(
    const int* __restrict__ Xi, const float* __restrict__ Xv,
    const float* __restrict__ emb,
    const float* __restrict__ cw, const float* __restrict__ cb,
    const float* __restrict__ Wout, const float* __restrict__ bout,
    const float* __restrict__ W1, const float* __restrict__ W2,
    u16* __restrict__ x0b, u16* __restrict__ w1bt, u16* __restrict__ w2bt,
    float* __restrict__ out) {
  __shared__ __align__(16) u16 sbuf[4][KP1_];
  __shared__ __align__(16) float tile[64][68];
  const int blk = blockIdx.x;
  const int tid = threadIdx.x;
  if (blk < B_ / 4) {
    const int w = tid >> 6, lane = tid & 63;
    const int b = blk * 4 + w;
    const int* xi = Xi + b * F_;

    float x0r[7];
    #pragma unroll
    for (int i = 0; i < 7; ++i) {
      int e = i * 64 + lane;
      float v = 0.f;
      if (e < 416) {
        int f = e >> 4;
        int idx = xi[f];
        v = emb[((size_t)f * N_ + idx) * M_ + (e & 15)];
      } else if (e < D_) {
        v = Xv[b * NUM_ + (e - 416)];
      }
      x0r[i] = v;
      sbuf[w][e] = f2bf_bits(v);
    }
    sbuf[w][448 + lane] = 0;

    float xr[7];
    #pragma unroll
    for (int i = 0; i < 7; ++i) xr[i] = x0r[i];
    for (int l = 0; l < L_; ++l) {
      float wl[7], bl[7];
      #pragma unroll
      for (int i = 0; i < 7; ++i) {
        int e = i * 64 + lane;
        if (e < D_) {
          int d = (e < 416) ? (13 + e) : (e - 416);
          wl[i] = cw[l * D_ + d]; bl[i] = cb[l * D_ + d];
        } else { wl[i] = 0.f; bl[i] = 0.f; }
      }
      float s = 0.f;
      #pragma unroll
      for (int i = 0; i < 7; ++i) s += xr[i] * wl[i];
      #pragma unroll
      for (int off = 32; off; off >>= 1) s += __shfl_xor(s, off);
      #pragma unroll
      for (int i = 0; i < 7; ++i) xr[i] = x0r[i] * s + bl[i] + xr[i];
    }

    __syncthreads();
    ((uint4*)(x0b + (size_t)b * KP1_))[lane] = ((const uint4*)sbuf[w])[lane];

    float s = 0.f;
    #pragma unroll
    for (int i = 0; i < 7; ++i) {
      int e = i * 64 + lane;
      if (e < D_) {
        int d = (e < 416) ? (13 + e) : (e - 416);
        s += xr[i] * Wout[H_ + d];
      }
    }
    #pragma unroll
    for (int off = 32; off; off >>= 1) s += __shfl_xor(s, off);
    if (lane == 0) out[b] = s + bout[0];
  } else {
    int pid = blk - B_ / 4;
    if (pid < 112) {
      // W1 -> w1bt[n][e]: e-tile ti (0..6), n-tile tj (0..15)
      const int ti = pid >> 4, tj = pid & 15;
      const int e0 = ti * 64, c0 = tj * 64;
      #pragma unroll
      for (int it = 0; it < 4; ++it) {
        int el = it * 16 + (tid >> 4);
        int e = e0 + el;
        int d = (e < 416) ? (13 + e) : ((e < D_) ? (e - 416) : -1);
        float4 v = make_float4(0.f, 0.f, 0.f, 0.f);
        if (d >= 0) v = *(const float4*)&W1[(size_t)d * H_ + c0 + (tid & 15) * 4];
        *(float4*)&tile[el][(tid & 15) * 4] = v;
      }
      __syncthreads();
      const int nl = tid >> 2, ks = (tid & 3) * 16;
      u16 tmp[16];
      #pragma unroll
      for (int x = 0; x < 16; ++x) tmp[x] = f2bf_bits(tile[ks + x][nl]);
      uint4* dst = (uint4*)&w1bt[(size_t)(c0 + nl) * KP1_ + e0 + ks];
      dst[0] = *(uint4*)&tmp[0];
      dst[1] = *(uint4*)&tmp[8];
    } else {
      pid -= 112;
      const int ti = pid >> 4, tj = pid & 15;
      const int k0 = ti * 64, c0 = tj * 64;
      #pragma unroll
      for (int it = 0; it < 4; ++it) {
        int kl = it * 16 + (tid >> 4);
        *(float4*)&tile[kl][(tid & 15) * 4] =
            *(const float4*)&W2[(size_t)(k0 + kl) * H_ + c0 + (tid & 15) * 4];
      }
      __syncthreads();
      const int nl = tid >> 2, ks = (tid & 3) * 16;
      u16 tmp[16];
      #pragma unroll
      for (int x = 0; x < 16; ++x) tmp[x] = f2bf_bits(tile[ks + x][nl]);
      uint4* dst = (uint4*)&w2bt[(size_t)(c0 + nl) * H_ + k0 + ks];
      dst[0] = *(uint4*)&tmp[0];
      dst[1] = *(uint4*)&tmp[8];
    }
  }
}

#define BARR __builtin_amdgcn_s_barrier()
#define SBR  __builtin_amdgcn_sched_barrier(0)
#define VM6  asm volatile("s_waitcnt vmcnt(6)" ::: "memory")
#define VM0  asm volatile("s_waitcnt vmcnt(0)" ::: "memory")
#define MM(ACC) do { \
  __builtin_amdgcn_s_setprio(1); \
  _Pragma("unroll") \
  for (int mi = 0; mi < 4; ++mi) { \
    _Pragma("unroll") \
    for (int ni = 0; ni < 4; ++ni) \
      ACC[mi][ni] = __builtin_amdgcn_mfma_f32_16x16x32_bf16(af[mi], bfc[ni], ACC[mi][ni], 0, 0, 0); \
  } \
  __builtin_amdgcn_s_setprio(0); \
} while (0)

// 256x256 tile, BK=64, 8 waves (2x4), 2-buffer LDS ring at kk-half granularity,
// m201 8-phase schedule: 1 half-tile staged per phase, vmcnt(6) ONLY at P3/P7,
// every half has 6-7 phases of flight. Issue slots (iter j, t0=2j, t1=2j+1):
//   P0:A(t1)k1  P1:B(t0+2)k0  P2:A(t0+2)k0  P3:B(t0+2)k1 [VM6]
//   P4:A(t0+2)k1  P5:B(t1+2)k0  P6:A(t1+2)k0  P7:B(t1+2)k1 [VM6]
// WAR: each slot overwritten exactly 1 phase after its last read (barrier-ordered).
// LDS per kk-half [256][32] u16, swizzle slot ^= (row>>1)&3 (2 lanes/bank-quad, free).
// MODE 0: C = bf16(relu(A@BT^T + bias)).  MODE 1: out[row] += sum_col relu(.)*Wout[col].
template<int MODE>
__global__ __launch_bounds__(512, 2) void gemm256(
    const u16* __restrict__ A, const u16* __restrict__ BT,
    const float* __restrict__ bias, u16* __restrict__ C,
    const float* __restrict__ Wout, float* __restrict__ out,
    int N, int K) {
  __shared__ __align__(16) u16 As[2][2][256 * 32];
  __shared__ __align__(16) u16 Bs[2][2][256 * 32];
  const int nbx = N >> 8;
  const int cpx = gridDim.x >> 3;
  const int swz = (blockIdx.x & 7) * cpx + (blockIdx.x >> 3);
  const int bx = swz % nbx;
  const int by = swz / nbx;
  const int tid = threadIdx.x;
  const int l = tid & 63;
  const int w = tid >> 6;
  const int wr = w >> 2, wc = w & 3;
  const int niter = K >> 7;   // 4 for K=512, 8 for K=1024

  // staging: thread -> (row r = tid>>2, chunk c = tid&3), source pre-swizzled c^((r>>1)&3)
  const int sr = tid >> 2;
  const int scs = ((tid & 3) ^ ((tid >> 3) & 3)) * 8;   // u16 within 32-col half
  const u16* gA0 = A  + (size_t)(by * 256 + sr) * K + scs;
  const u16* gB0 = BT + (size_t)(bx * 256 + sr) * K + scs;
  const int dst0 = tid * 8;   // u16 units within half-block

  auto stgA = [&](int t, int kk) {
    const u16* s = gA0 + t * 64 + kk * 32;
    __builtin_amdgcn_global_load_lds(
        (const __attribute__((address_space(1))) void*)s,
        (__attribute__((address_space(3))) void*)&As[t & 1][kk][dst0], 16, 0, 0);
    __builtin_amdgcn_global_load_lds(
        (const __attribute__((address_space(1))) void*)(s + (size_t)128 * K),
        (__attribute__((address_space(3))) void*)&As[t & 1][kk][dst0 + 4096], 16, 0, 0);
  };
  auto stgB = [&](int t, int kk) {
    const u16* s = gB0 + t * 64 + kk * 32;
    __builtin_amdgcn_global_load_lds(
        (const __attribute__((address_space(1))) void*)s,
        (__attribute__((address_space(3))) void*)&Bs[t & 1][kk][dst0], 16, 0, 0);
    __builtin_amdgcn_global_load_lds(
        (const __attribute__((address_space(1))) void*)(s + (size_t)128 * K),
        (__attribute__((address_space(3))) void*)&Bs[t & 1][kk][dst0 + 4096], 16, 0, 0);
  };

  // fragment reads: row*64B + swizzled 16B slot
  const int fr = l & 15, g = l >> 4;
  const int slot = (g ^ ((fr >> 1) & 3)) * 16;
  const int aoff = (wr * 128 + fr) * 64 + slot;
  const int boff = (wc * 64 + fr) * 64 + slot;

  bf16x8 af[4], bfc[4];
  auto rdA = [&](int buf, int kk, int mlo) {
    const char* base = (const char*)&As[buf][kk][0];
    #pragma unroll
    for (int m = 0; m < 4; ++m)
      af[m] = *(const bf16x8*)(base + aoff + (mlo + m) * 1024);
  };
  auto rdB = [&](int buf, int kk) {
    const char* base = (const char*)&Bs[buf][kk][0];
    #pragma unroll
    for (int n = 0; n < 4; ++n)
      bfc[n] = *(const bf16x8*)(base + boff + n * 1024);
  };

  f32x4 accLo[4][4] = {};
  f32x4 accHi[4][4] = {};

  // prologue: tile0 all 4 halves + 3 halves of tile1 in flight
  stgA(0, 0); stgB(0, 0); stgA(0, 1); stgB(0, 1);
  stgB(1, 0); stgA(1, 0); stgB(1, 1);
  VM6;    // tile0 complete; {B1k0, A1k0, B1k1} outstanding
  BARR;

  for (int j = 0; j < niter; ++j) {
    const int t1 = 2 * j + 1;
    const bool stg = (j + 1 < niter);
    // P0: t0 kk0 m0-3 + B
    rdA(0, 0, 0); rdB(0, 0);
    stgA(t1, 1);
    SBR; BARR; MM(accLo); BARR;
    // P1: t0 kk0 m4-7
    rdA(0, 0, 4);
    if (stg) stgB(t1 + 1, 0);
    SBR; BARR; MM(accHi); BARR;
    // P2: t0 kk1 m0-3 + B
    rdA(0, 1, 0); rdB(0, 1);
    if (stg) stgA(t1 + 1, 0);
    SBR; BARR; MM(accLo); BARR;
    // P3: t0 kk1 m4-7   [wait point]
    rdA(0, 1, 4);
    if (stg) stgB(t1 + 1, 1);
    SBR; BARR; MM(accHi);
    if (stg) { VM6; } else { VM0; }
    BARR;
    // P4: t1 kk0 m0-3 + B
    rdA(1, 0, 0); rdB(1, 0);
    if (stg) stgA(t1 + 1, 1);
    SBR; BARR; MM(accLo); BARR;
    // P5: t1 kk0 m4-7
    rdA(1, 0, 4);
    if (stg) stgB(t1 + 2, 0);
    SBR; BARR; MM(accHi); BARR;
    // P6: t1 kk1 m0-3 + B
    rdA(1, 1, 0); rdB(1, 1);
    if (stg) stgA(t1 + 2, 0);
    SBR; BARR; MM(accLo); BARR;
    // P7: t1 kk1 m4-7   [wait point]
    rdA(1, 1, 4);
    if (stg) stgB(t1 + 2, 1);
    SBR; BARR; MM(accHi);
    if (stg) { VM6; BARR; }
  }

  const int ccol0 = bx * 256 + wc * 64;
  const int row0 = by * 256 + wr * 128 + g * 4;
  if (MODE == 0) {
    #pragma unroll
    for (int n = 0; n < 4; ++n) {
      int col = ccol0 + n * 16 + fr;
      float bv = bias[col];
      #pragma unroll
      for (int m = 0; m < 4; ++m)
        #pragma unroll
        for (int r = 0; r < 4; ++r) {
          float v0 = fmaxf(accLo[m][n][r] + bv, 0.f);
          C[(size_t)(row0 + m * 16 + r) * N + col] = f2bf_bits(v0);
          float v1 = fmaxf(accHi[m][n][r] + bv, 0.f);
          C[(size_t)(row0 + 64 + m * 16 + r) * N + col] = f2bf_bits(v1);
        }
    }
  } else {
    float bv[4], wv[4];
    #pragma unroll
    for (int n = 0; n < 4; ++n) {
      int col = ccol0 + n * 16 + fr;
      bv[n] = bias[col]; wv[n] = Wout[col];
    }
    #pragma unroll
    for (int m = 0; m < 4; ++m)
      #pragma unroll
      for (int r = 0; r < 4; ++r) {
        float s0 = 0.f, s1 = 0.f;
        #pragma unroll
        for (int n = 0; n < 4; ++n) {
          s0 = fmaf(fmaxf(accLo[m][n][r] + bv[n], 0.f), wv[n], s0);
          s1 = fmaf(fmaxf(accHi[m][n][r] + bv[n], 0.f), wv[n], s1);
        }
        s0 += __shfl_xor(s0, 1); s0 += __shfl_xor(s0, 2);
        s0 += __shfl_xor(s0, 4); s0 += __shfl_xor(s0, 8);
        s1 += __shfl_xor(s1, 1); s1 += __shfl_xor(s1, 2);
        s1 += __shfl_xor(s1, 4); s1 += __shfl_xor(s1, 8);
        if (fr == 0) {
          atomicAdd(out + row0 + m * 16 + r, s0);
          atomicAdd(out + row0 + 64 + m * 16 + r, s1);
        }
      }
  }
}

extern "C" void kernel_launch(void* const* d_in, const int* in_sizes, int n_in,
                              void* d_out, int out_size, void* d_ws, size_t ws_size,
                              hipStream_t stream) {
  const int*   Xi   = (const int*)d_in[0];
  const float* Xv   = (const float*)d_in[1];
  const float* emb  = (const float*)d_in[2];
  const float* cw   = (const float*)d_in[3];
  const float* cb   = (const float*)d_in[4];
  const float* W1   = (const float*)d_in[5];
  const float* b1   = (const float*)d_in[6];
  const float* W2   = (const float*)d_in[7];
  const float* b2   = (const float*)d_in[8];
  const float* Wout = (const float*)d_in[9];
  const float* bout = (const float*)d_in[10];
  float* out = (float*)d_out;

  char* ws = (char*)d_ws;
  size_t off = 0;
  auto alloc = [&](size_t bytes) {
    void* p = ws + off; off += (bytes + 255) & ~(size_t)255; return p;
  };
  u16* x0b  = (u16*)alloc((size_t)B_ * KP1_ * 2);
  u16* w1bt = (u16*)alloc((size_t)H_ * KP1_ * 2);
  u16* w2bt = (u16*)alloc((size_t)H_ * H_ * 2);
  u16* h1   = (u16*)alloc((size_t)B_ * H_ * 2);

  hipLaunchKernelGGL(fused_front, dim3(B_ / 4 + 112 + 256), dim3(256), 0, stream,
                     Xi, Xv, emb, cw, cb, Wout, bout, W1, W2, x0b, w1bt, w2bt, out);
  hipLaunchKernelGGL((gemm256<0>), dim3((B_ / 256) * (H_ / 256)), dim3(512), 0, stream,
                     x0b, w1bt, b1, h1, nullptr, nullptr, H_, KP1_);
  hipLaunchKernelGGL((gemm256<1>), dim3((B_ / 256) * (H_ / 256)), dim3(512), 0, stream,
                     h1, w2bt, b2, nullptr, Wout, out, H_, H_);
}